// Round 7
// baseline (50.599 us; speedup 1.0000x reference)
//
#include <hip/hip_runtime.h>
#include <math.h>
#include <cfloat>

#define BLOCK 256
#define QPT 8     // queries per thread
#define CS  128   // refs per chunk (7-bit local index packs into mantissa low bits)

typedef float f32x2 __attribute__((ext_vector_type(2)));
typedef float f32x4 __attribute__((ext_vector_type(4)));
typedef unsigned long long u64;

static __device__ __forceinline__ unsigned umin32(unsigned a, unsigned b) {
    return a < b ? a : b;                       // v_min_u32 / fuses to v_min3_u32
}
static __device__ __forceinline__ f32x2 vlo(f32x4 v) { return __builtin_shufflevector(v, v, 0, 1); }
static __device__ __forceinline__ f32x2 vhi(f32x4 v) { return __builtin_shufflevector(v, v, 2, 3); }

// Both chamfer directions in ONE dispatch: blockIdx.z < Zn -> src->dst (refs =
// dst), else dst->src. Refs staged in LDS pair-packed:
//   lds4[2p]   = (-2x_a, -2x_b, -2y_a, -2y_b)      a = ref 2p, b = ref 2p+1
//   lds4[2p+1] = (-2z_a, -2z_b, w_a, w_b),  w = ||r||^2 + 64
// Hot loop per 2 refs per query: 3 v_pk_fma_f32 + 2 v_and_or_b32 + v_min3_u32
// = 3 issue slots/pair. R6 measured ~6.4 slots/pair at VGPR_Count=40: the
// compiler was REMATERIALIZING the duplicated query pairs (v_mov x2 per pair
// per use) instead of holding them. Fix: opaque empty-asm pin on each f32x2
// forces a live VGPR pair (zero instructions emitted, ~48 extra VGPRs held).
// e = d^2 + 64 - ||q||^2 > 0, so positive-float u32 compare is
// order-preserving; low 7 mantissa bits carry the local ref index (selection
// perturbed only within a ~1e-3 d^2 window; the reduce kernel recomputes the
// winning distance EXACTLY from raw coords). Epilogue: one device-scope
// atomicMin(u64) per (query, chunk), key = (masked_e << 32) | global_idx —
// min is commutative/idempotent => deterministic; ties pick lowest global
// index (matches jnp.argmin first-occurrence).
__global__ __launch_bounds__(BLOCK, 4)
void chamfer_min_kernel(const float* __restrict__ pc_src,
                        const float* __restrict__ pc_dst,
                        u64* __restrict__ part,   // [B*M] dir0 then [B*N] dir1
                        int M, int N, int B, int Zn) {
    __shared__ f32x4 lds4[CS];                    // 64 pairs x 2 quads = 2 KiB

    const int b = blockIdx.y;
    const int z = blockIdx.z;
    const int dir = (z >= Zn) ? 1 : 0;
    const int chunk = dir ? (z - Zn) : z;

    const int NQ = dir ? N : M;
    const int NR = dir ? M : N;
    const float* pcq = dir ? pc_dst : pc_src;
    const float* pcr = dir ? pc_src : pc_dst;
    u64* pp = part + (dir ? (size_t)B * M : (size_t)0) + (size_t)b * NQ;

    const int n0 = chunk * CS;
    const int tid = threadIdx.x;

    // Stage 64 ref pairs (threads 0..63; float2 global loads, coalesced).
    const float* rbase = pcr + (size_t)b * 3 * NR + n0;
    if (tid < CS / 2) {
        const int p = tid;
        const f32x2 rx = *(const f32x2*)(rbase + 2 * p);
        const f32x2 ry = *(const f32x2*)(rbase + NR + 2 * p);
        const f32x2 rz = *(const f32x2*)(rbase + 2 * NR + 2 * p);
        f32x4 w0, w1;
        w0.x = -2.0f * rx.x; w0.y = -2.0f * rx.y;
        w0.z = -2.0f * ry.x; w0.w = -2.0f * ry.y;
        w1.x = -2.0f * rz.x; w1.y = -2.0f * rz.y;
        w1.z = fmaf(rx.x, rx.x, fmaf(ry.x, ry.x, rz.x * rz.x)) + 64.0f;
        w1.w = fmaf(rx.y, rx.y, fmaf(ry.y, ry.y, rz.y * rz.y)) + 64.0f;
        lds4[2 * p]     = w0;
        lds4[2 * p + 1] = w1;
    }

    // QPT query points per thread, coordinates duplicated into f32x2 pairs and
    // PINNED into VGPR pairs (opaque asm) so the loop has zero v_mov overhead.
    const int q0 = blockIdx.x * (BLOCK * QPT) + tid;
    const float* qb = pcq + (size_t)b * 3 * NQ;
    f32x2 qx2[QPT], qy2[QPT], qz2[QPT];
    unsigned kmin[QPT];
#pragma unroll
    for (int j = 0; j < QPT; ++j) {
        const int q = q0 + j * BLOCK;
        const float x = qb[q], y = qb[NQ + q], zz = qb[2 * NQ + q];
        qx2[j] = (f32x2){x, x};
        qy2[j] = (f32x2){y, y};
        qz2[j] = (f32x2){zz, zz};
        asm("" : "+v"(qx2[j]), "+v"(qy2[j]), "+v"(qz2[j]));  // pin pairs, no code
        kmin[j] = 0xFFFFFFFFu;
    }

    __syncthreads();

    const unsigned mask = ~(unsigned)(CS - 1);
#pragma unroll 4
    for (int p = 0; p < CS / 2; ++p) {
        const f32x4 w0 = lds4[2 * p];       // broadcast ds_read_b128
        const f32x4 w1 = lds4[2 * p + 1];
        const f32x2 rx2 = vlo(w0), ry2 = vhi(w0);
        const f32x2 rz2 = vlo(w1), rw2 = vhi(w1);
#pragma unroll
        for (int j = 0; j < QPT; ++j) {
            f32x2 e;
            asm("v_pk_fma_f32 %0, %1, %2, %3"
                : "=v"(e) : "v"(qz2[j]), "v"(rz2), "v"(rw2));
            asm("v_pk_fma_f32 %0, %1, %2, %0"
                : "+v"(e) : "v"(qy2[j]), "v"(ry2));
            asm("v_pk_fma_f32 %0, %1, %2, %0"
                : "+v"(e) : "v"(qx2[j]), "v"(rx2));
            const unsigned k0 = (__float_as_uint(e.x) & mask) | (unsigned)(2 * p);
            const unsigned k1 = (__float_as_uint(e.y) & mask) | (unsigned)(2 * p + 1);
            kmin[j] = umin32(umin32(k0, k1), kmin[j]);   // v_min3_u32
        }
    }

#pragma unroll
    for (int j = 0; j < QPT; ++j) {
        const int q = q0 + j * BLOCK;
        const unsigned gidx = (unsigned)n0 + (kmin[j] & (unsigned)(CS - 1));
        const u64 key = ((u64)(kmin[j] & mask) << 32) | (u64)gidx;
        atomicMin(&pp[q], key);
    }
}

// Tiny epilogue: one thread per query (both directions concatenated in part),
// decode global argmin, recompute the winning distance EXACTLY from raw
// coords, weight by sigma, block-reduce, one atomicAdd per block.
__global__ void chamfer_reduce_kernel(const float* __restrict__ pc_src,
                                      const float* __restrict__ pc_dst,
                                      const float* __restrict__ sig_src,
                                      const float* __restrict__ sig_dst,
                                      const u64* __restrict__ part,
                                      float* __restrict__ out,
                                      int M, int N, int B) {
    __shared__ float red[BLOCK];
    const int TT = blockIdx.x * BLOCK + threadIdx.x;
    const int dir = (TT >= B * M);           // uniform per block (B*M % 256 == 0)
    const int t = dir ? TT - B * M : TT;     // t = b*NQ + q

    const int NQ = dir ? N : M;
    const int NR = dir ? M : N;
    const float* pcq  = dir ? pc_dst : pc_src;
    const float* pcr  = dir ? pc_src : pc_dst;
    const float* sigq = dir ? sig_dst : sig_src;
    const float* sigr = dir ? sig_src : sig_dst;
    const float scale = 1.0f / (float)(B * NQ);

    const int b = t / NQ;
    const int q = t - b * NQ;

    const int gidx = (int)(unsigned)part[TT];   // low 32 bits = global argmin

    const float* qbase = pcq + (size_t)b * 3 * NQ;
    const float* rbase = pcr + (size_t)b * 3 * NR;
    const float dx = qbase[q]          - rbase[gidx];
    const float dy = qbase[NQ + q]     - rbase[NR + gidx];
    const float dz = qbase[2 * NQ + q] - rbase[2 * NR + gidx];
    const float dist = sqrtf(fmaf(dx, dx, fmaf(dy, dy, dz * dz)));

    const float s = 0.5f * (sigq[t] + sigr[(size_t)b * NR + gidx]);
    red[threadIdx.x] = dist * s * scale;
    __syncthreads();

    for (int w = BLOCK / 2; w > 0; w >>= 1) {
        if (threadIdx.x < w) red[threadIdx.x] += red[threadIdx.x + w];
        __syncthreads();
    }
    if (threadIdx.x == 0) atomicAdd(out, red[0]);
}

extern "C" void kernel_launch(void* const* d_in, const int* in_sizes, int n_in,
                              void* d_out, int out_size, void* d_ws, size_t ws_size,
                              hipStream_t stream) {
    const float* pc_src  = (const float*)d_in[0];   // [B,3,M]
    const float* pc_dst  = (const float*)d_in[1];   // [B,3,N]
    const float* sig_src = (const float*)d_in[2];   // [B,M]
    const float* sig_dst = (const float*)d_in[3];   // [B,N]
    float* out = (float*)d_out;

    const int B = 8;
    const int M = in_sizes[2] / B;   // 4096
    const int N = in_sizes[3] / B;   // 4096
    const int NMAX = (M > N) ? M : N;

    const int Zn = N / CS;           // chunks for dir0 (refs = dst)
    const int Zm = M / CS;           // chunks for dir1 (refs = src)

    u64* part = (u64*)d_ws;          // B*M dir0 keys, then B*N dir1 keys
    const size_t partBytes = (size_t)B * (M + N) * sizeof(u64);   // 512 KiB

    hipMemsetAsync(part, 0xFF, partBytes, stream);   // u64 max sentinels
    hipMemsetAsync(d_out, 0, sizeof(float), stream);

    {   // both directions, one dispatch: grid (2, 8, 64) = 1024 blocks
        dim3 grid(NMAX / (BLOCK * QPT), B, Zn + Zm);
        chamfer_min_kernel<<<grid, BLOCK, 0, stream>>>(
            pc_src, pc_dst, part, M, N, B, Zn);
    }
    {   // epilogue over all queries of both directions
        dim3 rgrid((B * (M + N)) / BLOCK);
        chamfer_reduce_kernel<<<rgrid, BLOCK, 0, stream>>>(
            pc_src, pc_dst, sig_src, sig_dst, part, out, M, N, B);
    }
}

// Round 8
// 49.548 us; speedup vs baseline: 1.0212x; 1.0212x over previous
//
#include <hip/hip_runtime.h>
#include <math.h>
#include <cfloat>

#define BLOCK 256
#define QPT 8     // queries per thread
#define CS  64    // refs per chunk: local idx 0..63 = VOP3 inline constants

typedef float f32x2 __attribute__((ext_vector_type(2)));
typedef float f32x4 __attribute__((ext_vector_type(4)));
typedef unsigned long long u64;

// Both chamfer directions in ONE dispatch: blockIdx.z < Zn -> src->dst (refs =
// dst), else dst->src. Refs staged in LDS pair-packed:
//   lds4[2p]   = (-2x_a, -2x_b, -2y_a, -2y_b)      a = ref 2p, b = ref 2p+1
//   lds4[2p+1] = (-2z_a, -2z_b, w_a, w_b),  w = ||r||^2 + 64
// R7 post-mortem: v_pk_fma_f32 is 2 issue slots on CDNA4 (157.3 TF spec =
// full-rate SCALAR fma; packed at 1 slot would imply 314 TF) and the
// intrinsic path carried ~3 extra mov slots/pair that source-level hints
// could not remove. So the 9-inst sequence per 2 refs is emitted as ONE
// inline-asm block: 6 v_fma_f32 + 2 v_and_or_b32 + 1 v_min3_u32
// = 4.5 slots/pair exactly. e = d^2 + 64 - ||q||^2 > 0 so positive-float u32
// compare is order-preserving; low 6 mantissa bits carry the local ref index
// (the reduce kernel recomputes the winning distance EXACTLY from raw
// coords). Epilogue: one device-scope atomicMin(u64) per (query, chunk),
// key = (masked_e << 32) | global_idx — min is commutative/idempotent =>
// deterministic; ties pick lowest global index (jnp.argmin first-occurrence).
__global__ __launch_bounds__(BLOCK, 4)
void chamfer_min_kernel(const float* __restrict__ pc_src,
                        const float* __restrict__ pc_dst,
                        u64* __restrict__ part,   // [B*M] dir0 then [B*N] dir1
                        int M, int N, int B, int Zn) {
    __shared__ f32x4 lds4[CS];                    // 32 pairs x 2 quads = 1 KiB

    const int b = blockIdx.y;
    const int z = blockIdx.z;
    const int dir = (z >= Zn) ? 1 : 0;
    const int chunk = dir ? (z - Zn) : z;

    const int NQ = dir ? N : M;
    const int NR = dir ? M : N;
    const float* pcq = dir ? pc_dst : pc_src;
    const float* pcr = dir ? pc_src : pc_dst;
    u64* pp = part + (dir ? (size_t)B * M : (size_t)0) + (size_t)b * NQ;

    const int n0 = chunk * CS;
    const int tid = threadIdx.x;

    // Stage 32 ref pairs (threads 0..31; float2 global loads, coalesced).
    const float* rbase = pcr + (size_t)b * 3 * NR + n0;
    if (tid < CS / 2) {
        const int p = tid;
        const f32x2 rx = *(const f32x2*)(rbase + 2 * p);
        const f32x2 ry = *(const f32x2*)(rbase + NR + 2 * p);
        const f32x2 rz = *(const f32x2*)(rbase + 2 * NR + 2 * p);
        f32x4 w0, w1;
        w0.x = -2.0f * rx.x; w0.y = -2.0f * rx.y;
        w0.z = -2.0f * ry.x; w0.w = -2.0f * ry.y;
        w1.x = -2.0f * rz.x; w1.y = -2.0f * rz.y;
        w1.z = fmaf(rx.x, rx.x, fmaf(ry.x, ry.x, rz.x * rz.x)) + 64.0f;
        w1.w = fmaf(rx.y, rx.y, fmaf(ry.y, ry.y, rz.y * rz.y)) + 64.0f;
        lds4[2 * p]     = w0;
        lds4[2 * p + 1] = w1;
    }

    // QPT query points per thread (scalar coords; scalar v_fma is full-rate).
    const int q0 = blockIdx.x * (BLOCK * QPT) + tid;
    const float* qb = pcq + (size_t)b * 3 * NQ;
    float qx[QPT], qy[QPT], qz[QPT];
    unsigned kmin[QPT];
#pragma unroll
    for (int j = 0; j < QPT; ++j) {
        const int q = q0 + j * BLOCK;
        qx[j] = qb[q];
        qy[j] = qb[NQ + q];
        qz[j] = qb[2 * NQ + q];
        kmin[j] = 0xFFFFFFFFu;
    }

    __syncthreads();

    const unsigned mask = ~(unsigned)(CS - 1);   // 0xFFFFFFC0, lives in an SGPR
#pragma unroll
    for (int p = 0; p < CS / 2; ++p) {           // FULL unroll: idx are inline consts
        const f32x4 w0 = lds4[2 * p];            // broadcast ds_read_b128
        const f32x4 w1 = lds4[2 * p + 1];
#pragma unroll
        for (int j = 0; j < QPT; ++j) {
            float e0, e1;
            asm("v_fma_f32 %1, %5, %10, %12\n\t"   // e0 = qz*rz_a + w_a
                "v_fma_f32 %2, %5, %11, %13\n\t"   // e1 = qz*rz_b + w_b
                "v_fma_f32 %1, %4, %8, %1\n\t"     // e0 += qy*ry_a
                "v_fma_f32 %2, %4, %9, %2\n\t"     // e1 += qy*ry_b
                "v_fma_f32 %1, %3, %6, %1\n\t"     // e0 += qx*rx_a
                "v_fma_f32 %2, %3, %7, %2\n\t"     // e1 += qx*rx_b
                "v_and_or_b32 %1, %1, %14, %15\n\t" // key_a = (bits&mask)|2p
                "v_and_or_b32 %2, %2, %14, %16\n\t" // key_b = (bits&mask)|2p+1
                "v_min3_u32 %0, %1, %2, %0"         // kmin = min3(key_a,key_b,kmin)
                : "+v"(kmin[j]), "=&v"(e0), "=&v"(e1)
                : "v"(qx[j]), "v"(qy[j]), "v"(qz[j]),
                  "v"(w0.x), "v"(w0.y), "v"(w0.z), "v"(w0.w),
                  "v"(w1.x), "v"(w1.y), "v"(w1.z), "v"(w1.w),
                  "s"(mask), "i"(2 * p), "i"(2 * p + 1));
        }
    }

#pragma unroll
    for (int j = 0; j < QPT; ++j) {
        const int q = q0 + j * BLOCK;
        const unsigned gidx = (unsigned)n0 + (kmin[j] & (unsigned)(CS - 1));
        const u64 key = ((u64)(kmin[j] & mask) << 32) | (u64)gidx;
        atomicMin(&pp[q], key);
    }
}

// Tiny epilogue: one thread per query (both directions concatenated in part),
// decode global argmin, recompute the winning distance EXACTLY from raw
// coords, weight by sigma, block-reduce, one atomicAdd per block.
__global__ void chamfer_reduce_kernel(const float* __restrict__ pc_src,
                                      const float* __restrict__ pc_dst,
                                      const float* __restrict__ sig_src,
                                      const float* __restrict__ sig_dst,
                                      const u64* __restrict__ part,
                                      float* __restrict__ out,
                                      int M, int N, int B) {
    __shared__ float red[BLOCK];
    const int TT = blockIdx.x * BLOCK + threadIdx.x;
    const int dir = (TT >= B * M);           // uniform per block (B*M % 256 == 0)
    const int t = dir ? TT - B * M : TT;     // t = b*NQ + q

    const int NQ = dir ? N : M;
    const int NR = dir ? M : N;
    const float* pcq  = dir ? pc_dst : pc_src;
    const float* pcr  = dir ? pc_src : pc_dst;
    const float* sigq = dir ? sig_dst : sig_src;
    const float* sigr = dir ? sig_src : sig_dst;
    const float scale = 1.0f / (float)(B * NQ);

    const int b = t / NQ;
    const int q = t - b * NQ;

    const int gidx = (int)(unsigned)part[TT];   // low 32 bits = global argmin

    const float* qbase = pcq + (size_t)b * 3 * NQ;
    const float* rbase = pcr + (size_t)b * 3 * NR;
    const float dx = qbase[q]          - rbase[gidx];
    const float dy = qbase[NQ + q]     - rbase[NR + gidx];
    const float dz = qbase[2 * NQ + q] - rbase[2 * NR + gidx];
    const float dist = sqrtf(fmaf(dx, dx, fmaf(dy, dy, dz * dz)));

    const float s = 0.5f * (sigq[t] + sigr[(size_t)b * NR + gidx]);
    red[threadIdx.x] = dist * s * scale;
    __syncthreads();

    for (int w = BLOCK / 2; w > 0; w >>= 1) {
        if (threadIdx.x < w) red[threadIdx.x] += red[threadIdx.x + w];
        __syncthreads();
    }
    if (threadIdx.x == 0) atomicAdd(out, red[0]);
}

extern "C" void kernel_launch(void* const* d_in, const int* in_sizes, int n_in,
                              void* d_out, int out_size, void* d_ws, size_t ws_size,
                              hipStream_t stream) {
    const float* pc_src  = (const float*)d_in[0];   // [B,3,M]
    const float* pc_dst  = (const float*)d_in[1];   // [B,3,N]
    const float* sig_src = (const float*)d_in[2];   // [B,M]
    const float* sig_dst = (const float*)d_in[3];   // [B,N]
    float* out = (float*)d_out;

    const int B = 8;
    const int M = in_sizes[2] / B;   // 4096
    const int N = in_sizes[3] / B;   // 4096
    const int NMAX = (M > N) ? M : N;

    const int Zn = N / CS;           // chunks for dir0 (refs = dst)
    const int Zm = M / CS;           // chunks for dir1 (refs = src)

    u64* part = (u64*)d_ws;          // B*M dir0 keys, then B*N dir1 keys
    const size_t partBytes = (size_t)B * (M + N) * sizeof(u64);   // 512 KiB

    hipMemsetAsync(part, 0xFF, partBytes, stream);   // u64 max sentinels
    hipMemsetAsync(d_out, 0, sizeof(float), stream);

    {   // both directions, one dispatch: grid (2, 8, 128) = 2048 blocks
        dim3 grid(NMAX / (BLOCK * QPT), B, Zn + Zm);
        chamfer_min_kernel<<<grid, BLOCK, 0, stream>>>(
            pc_src, pc_dst, part, M, N, B, Zn);
    }
    {   // epilogue over all queries of both directions
        dim3 rgrid((B * (M + N)) / BLOCK);
        chamfer_reduce_kernel<<<rgrid, BLOCK, 0, stream>>>(
            pc_src, pc_dst, sig_src, sig_dst, part, out, M, N, B);
    }
}